// Round 13
// baseline (182.396 us; speedup 1.0000x reference)
//
#include <hip/hip_runtime.h>

typedef _Float16 half8 __attribute__((ext_vector_type(8)));
typedef float floatx4 __attribute__((ext_vector_type(4)));

#define BB 8
#define CC 64
#define HH 128
#define WW 256
#define DD 64
#define GRID 256          // 1 block per CU; 8 free-running waves each
#define OPITCH 36         // wave-private Ob pitch (floats)

// out[b,d,h,w] = (1/64) sum_c L[b,c,h,w] * R[b,c,h,w-d], 0 where w<d.
// Banded Gram via mfma_f32_16x16x32_f16 (d = 64-16u+n-m algebra).
// R10-R16: delivery pinned at ~2.3 TB/s under EVERY lever inside the
//   phase-locked cooperative structure (blocks/CU, in-flight bytes, lgkm
//   barriers, issue smoothing, 3 address mappings, channel spread) -> the
//   wall is the block-wide barrier: every row, all 8 waves wait for the
//   SLOWEST of the block's 8192 loads, then stall in lockstep.
// R17: zero-barrier free-running waves. R8 tested wave-independence but
//   its 1-wave/16KB blocks only got ~5.3 waves/CU (LDS fragmentation).
//   Now: one 512-thread block/CU, each wave owns a PRIVATE 16KB arena
//   (Lw[32][64] + Rw[96][64] f16; Ob[64][36] f32 overlay) and runs R8's
//   verified self-sufficient task loop: 4 consecutive 32-w tiles of one
//   (b,h) row half. No __syncthreads anywhere; waves de-phase naturally,
//   so per-CU demand is continuous and a slow load parks 1 wave, not 8.
//   R-band overlap between consecutive tiles re-read through L1/L2/LLC
//   (R8 measured FETCH 67.8MB under the same redundancy).
__global__ __launch_bounds__(512, 2)
void corr_volume_mfma(const float* __restrict__ left,
                      const float* __restrict__ right,
                      float* __restrict__ out) {
    __shared__ alignas(16) unsigned char smem[131072];   // 8 x 16 KB arenas

    const int tid  = threadIdx.x;
    const int lane = tid & 63;
    const int wv   = tid >> 6;          // wave 0..7

    _Float16* const Lw = (_Float16*)(smem + wv * 16384);          // [32][64]
    _Float16* const Rw = (_Float16*)(smem + wv * 16384 + 4096);   // [96][64]
    float*    const Ob = (float*)(smem + wv * 16384);             // [64][36]

    // Wave -> (row, half): rows bid + j*256 (R11's concentrated mapping);
    // 2 waves per row (w-halves), 4 tiles each.
    const int bh   = blockIdx.x + (wv >> 1) * GRID;
    const int b    = bh >> 7;
    const int h    = bh & 127;
    const int half = wv & 1;

    const size_t chanStride = (size_t)HH * WW;      // 32768
    const size_t rowBase = (size_t)b * CC * chanStride + (size_t)h * WW;

    const int cg = lane >> 3;           // c-octet
    const int wq = (lane & 7) * 4;      // w quad within tile

    const float* lpb = left  + rowBase + (size_t)(cg * 8) * chanStride + wq;
    const float* rpb = right + rowBase + (size_t)(cg * 8) * chanStride + wq;

    const int n = lane & 15;            // MFMA col / A row
    const int q = lane >> 4;            // quad
    const float scale = 1.0f / 64.0f;

    #pragma unroll 1
    for (int t = 0; t < 4; ++t) {
        const int W0 = half * 128 + t * 32;     // tile base w

        // ---- issue this tile's loads (self-sufficient per wave) ----
        // L rows [W0, W0+32); R groups g: rows [g*32,(g+1)*32) hold
        // w' = W0-64+g*32+wq, valid iff W0-64+g*32 >= 0.
        float4 lv[8], ra[8], rbv[8], rx[8];
        #pragma unroll
        for (int c = 0; c < 8; ++c)
            lv[c] = *(const float4*)(lpb + (size_t)c * chanStride + W0);
        #pragma unroll
        for (int c = 0; c < 8; ++c)
            ra[c] = *(const float4*)(rpb + (size_t)c * chanStride + W0);
        if (W0 >= 32) {
            #pragma unroll
            for (int c = 0; c < 8; ++c)
                rbv[c] = *(const float4*)(rpb + (size_t)c * chanStride + (W0 - 32));
        }
        if (W0 >= 64) {
            #pragma unroll
            for (int c = 0; c < 8; ++c)
                rx[c] = *(const float4*)(rpb + (size_t)c * chanStride + (W0 - 64));
        }

        // ---- zero pad rows (w'<0); overlaps load latency ----
        if (W0 < 64) {
            const int nz8 = (64 - W0) * 8;      // half8 slots (row = 8 slots)
            half8 z = {0, 0, 0, 0, 0, 0, 0, 0};
            for (int zz = lane; zz < nz8; zz += 64)
                *(half8*)&Rw[zz * 8] = z;
        }

        // ---- cvt + stage (counted vmcnt waits, in issue order) ----
        {
            const float* lf = (const float*)lv;
            #pragma unroll
            for (int s = 0; s < 4; ++s) {
                const int j   = wq + s;
                const int col = (cg ^ (j & 7)) * 8;
                half8 v;
                #pragma unroll
                for (int c = 0; c < 8; ++c) v[c] = (_Float16)lf[c * 4 + s];
                *(half8*)&Lw[j * 64 + col] = v;
            }
        }
        {
            const float* rf = (const float*)ra;
            #pragma unroll
            for (int s = 0; s < 4; ++s) {
                const int j   = 64 + wq + s;
                const int col = (cg ^ (j & 7)) * 8;
                half8 v;
                #pragma unroll
                for (int c = 0; c < 8; ++c) v[c] = (_Float16)rf[c * 4 + s];
                *(half8*)&Rw[j * 64 + col] = v;
            }
        }
        if (W0 >= 32) {
            const float* rf = (const float*)rbv;
            #pragma unroll
            for (int s = 0; s < 4; ++s) {
                const int j   = 32 + wq + s;
                const int col = (cg ^ (j & 7)) * 8;
                half8 v;
                #pragma unroll
                for (int c = 0; c < 8; ++c) v[c] = (_Float16)rf[c * 4 + s];
                *(half8*)&Rw[j * 64 + col] = v;
            }
        }
        if (W0 >= 64) {
            const float* rf = (const float*)rx;
            #pragma unroll
            for (int s = 0; s < 4; ++s) {
                const int j   = wq + s;
                const int col = (cg ^ (j & 7)) * 8;
                half8 v;
                #pragma unroll
                for (int c = 0; c < 8; ++c) v[c] = (_Float16)rf[c * 4 + s];
                *(half8*)&Rw[j * 64 + col] = v;
            }
        }
        // Intra-wave lgkmcnt orders ds_write -> ds_read; no barrier needed.

        // ---------------- MFMA (R8-verified shape) ----------------
        floatx4 acc[2][5];
        #pragma unroll
        for (int tt = 0; tt < 2; ++tt)
            #pragma unroll
            for (int u = 0; u < 5; ++u)
                #pragma unroll
                for (int r = 0; r < 4; ++r)
                    acc[tt][u][r] = 0.0f;

        #pragma unroll
        for (int kk = 0; kk < 2; ++kk) {
            const int col = ((kk * 4 + q) ^ (n & 7)) * 8;
            half8 bfrag[2], afrag[6];
            #pragma unroll
            for (int tt = 0; tt < 2; ++tt)
                bfrag[tt] = *(const half8*)&Lw[(tt * 16 + n) * 64 + col];
            #pragma unroll
            for (int a = 0; a < 6; ++a)
                afrag[a] = *(const half8*)&Rw[(a * 16 + n) * 64 + col];
            #pragma unroll
            for (int tt = 0; tt < 2; ++tt)
                #pragma unroll
                for (int u = 0; u < 5; ++u)
                    acc[tt][u] = __builtin_amdgcn_mfma_f32_16x16x32_f16(
                        afrag[tt + u], bfrag[tt], acc[tt][u], 0, 0, 0);
        }
        // Fragment reads done before Ob overlay writes (same-wave lgkmcnt).

        // acc -> wave-private Ob[d][wloc]; d = 64-16u+n-m, m = q*4+r.
        #pragma unroll
        for (int tt = 0; tt < 2; ++tt) {
            const int wloc = tt * 16 + n;
            #pragma unroll
            for (int u = 0; u < 5; ++u) {
                #pragma unroll
                for (int r = 0; r < 4; ++r) {
                    const int d = 64 - 16 * u + n - (q * 4 + r);
                    if (d >= 0 && d < DD) {
                        Ob[d * OPITCH + wloc] = acc[tt][u][r] * scale;
                    }
                }
            }
        }

        // Stores: 8 instrs x (8 d-rows x 128 B). NT; drain under next task.
        #pragma unroll
        for (int ii = 0; ii < 8; ++ii) {
            const int d    = ii * 8 + (lane >> 3);
            const int wloc = (lane & 7) * 4;
            const floatx4 v = *(const floatx4*)&Ob[d * OPITCH + wloc];
            floatx4* dst = (floatx4*)&out[(((size_t)b * DD + d) * HH + h) * WW + W0 + wloc];
            __builtin_nontemporal_store(v, dst);
        }
    }
}

extern "C" void kernel_launch(void* const* d_in, const int* in_sizes, int n_in,
                              void* d_out, int out_size, void* d_ws, size_t ws_size,
                              hipStream_t stream) {
    const float* left  = (const float*)d_in[0];
    const float* right = (const float*)d_in[1];
    float* out = (float*)d_out;

    dim3 grid(GRID);    // 256 blocks = 1 per CU; 8 barrier-free waves each
    dim3 block(512);
    corr_volume_mfma<<<grid, block, 0, stream>>>(left, right, out);
}

// Round 14
// 174.207 us; speedup vs baseline: 1.0470x; 1.0470x over previous
//
#include <hip/hip_runtime.h>

typedef _Float16 half8 __attribute__((ext_vector_type(8)));
typedef float floatx4 __attribute__((ext_vector_type(4)));

#define BB 8
#define CC 64
#define HH 128
#define WW 256
#define DD 64
#define NROW 2            // phases per block; 2 rows per phase
#define GRID 256          // 1 block per CU; GRID*2*NROW == BB*HH
#define OPITCH 260        // Ob row pitch (floats)
#define ARENA 73728       // bytes per row arena (Lb 32K + Rb 40K)

// LDS-only barrier: lgkmcnt(0)+s_barrier; vmcnt loads/stores stay in
// flight across barriers, waited per-thread (counted) at the consuming cvt.
#define BAR() asm volatile("s_waitcnt lgkmcnt(0)\n\ts_barrier" ::: "memory")

// out[b,d,h,w] = (1/64) sum_c L[b,c,h,w] * R[b,c,h,w-d], 0 where w<d.
// Banded Gram via mfma_f32_16x16x32_f16 (d = 64-16u+n-m algebra).
// R6-R17 ledger: delivery rate pinned at ~2.3-2.4 TB/s across phase-locked
//   AND zero-barrier free-running structures, 1-16 waves/CU concurrency,
//   2x in-flight bytes, 3 address mappings, channel-spread, NT stores.
//   R17 (barrier-free) matched the rate exactly while moving 30% more
//   bytes -> the cap is NOT CU-side scheduling.
// R18: DRAM row-activation theory. Identical instruction-level pattern to
//   the 6.3 TB/s copy EXCEPT address sequence: we read 1KB chunks at
//   128KB stride -> every chunk opens a fresh DRAM row; tRC-limited banks
//   cap ~1KB/activation => ~2.3-2.8 TB/s chip — the measured plateau.
//   Fix: rows h, h+1 of the same (b,c) are ADJACENT 1KB blocks, so stage
//   TWO consecutive h-rows per block-phase: 1024-thread block = two
//   8-wave row-groups, each running the verified R11 per-wave code on its
//   own 72KB arena (144KB LDS). Both groups issue the same chunk position
//   at the same code point -> (c,h),(c,h+1) co-resident in the MC queue
//   -> 2KB row-hit runs (adjacent blocks extend to 4KB under loose sync).
//   Mapping bh = k*512 + 2*bid + rg keeps per-phase footprint dense.
__global__ __launch_bounds__(1024, 4)
void corr_volume_mfma(const float* __restrict__ left,
                      const float* __restrict__ right,
                      float* __restrict__ out) {
    // Two 72KB arenas. Per arena: Lb[256][64] f16 (32K) + Rb[320][64] f16
    // (40K); epilogue overlays Ob[64][OPITCH] f32 (66,560 B) per arena.
    __shared__ alignas(16) unsigned char smem[2 * ARENA];   // 147,456 B

    const int tid  = threadIdx.x;
    const int rg   = tid >> 9;          // row-group 0/1 (waves 0-7 / 8-15)
    const int t5   = tid & 511;         // index within row-group
    const int lane = tid & 63;
    const int wvl  = t5 >> 6;           // wave-in-group 0..7
    const int sw   = lane * 4;          // staged w rows sw..sw+3
    const int cg   = wvl;               // staged channel octet

    _Float16* const Lb = (_Float16*)(smem + rg * ARENA);
    _Float16* const Rb = (_Float16*)(smem + rg * ARENA + 32768);
    float*    const Ob = (float*)(smem + rg * ARENA);

    const size_t chanStride = (size_t)HH * WW;      // 32768

    float4 lv[8], rv[8];

    // Prologue: issue phase-0 loads (both row-groups together -> the
    // (c,h)/(c,h+1) chunk pairs enter the MC queue back-to-back).
    {
        const int bh = 2 * (int)blockIdx.x + rg;
        const size_t rowBase = (size_t)(bh >> 7) * CC * chanStride
                             + (size_t)(bh & 127) * WW;
        const float* lp = left  + rowBase + (size_t)(cg * 8) * chanStride + sw;
        const float* rp = right + rowBase + (size_t)(cg * 8) * chanStride + sw;
        #pragma unroll
        for (int c = 0; c < 8; ++c) {
            lv[c] = *(const float4*)(lp + (size_t)c * chanStride);
            rv[c] = *(const float4*)(rp + (size_t)c * chanStride);
        }
    }

    const int n = lane & 15;            // MFMA col (w) / A row
    const int q = lane >> 4;            // quad
    const int wbase = wvl * 32;         // this wave's w range
    const float scale = 1.0f / 64.0f;

    #pragma unroll
    for (int k = 0; k < NROW; ++k) {
        const int bh = k * 512 + 2 * (int)blockIdx.x + rg;
        const int b  = bh >> 7;
        const int h  = bh & 127;

        BAR();   // A: prior phase's Ob ds_reads done (k=0: orders nothing)

        // Re-zero the w'<0 pad rows of this arena (Ob overlay clobbers).
        {
            half8 z = {0, 0, 0, 0, 0, 0, 0, 0};
            *(half8*)&Rb[t5 * 8] = z;
        }

        // Transpose 8c x 4w from regs -> LDS. Per-thread counted vmcnt
        // waits for this phase's loads happen here; no cross-wave drain.
        {
            const float* lf = (const float*)lv;
            const float* rf = (const float*)rv;
            #pragma unroll
            for (int s = 0; s < 4; ++s) {
                const int w   = sw + s;
                const int col = (cg ^ (w & 7)) * 8;
                half8 lh, rh;
                #pragma unroll
                for (int c = 0; c < 8; ++c) {
                    lh[c] = (_Float16)lf[c * 4 + s];
                    rh[c] = (_Float16)rf[c * 4 + s];
                }
                *(half8*)&Lb[w * 64 + col]        = lh;
                *(half8*)&Rb[(w + 64) * 64 + col] = rh;
            }
        }

        // Refill, group 1 of 4 (L chunks 0-3) — regs just freed by cvt.
        const float* lp2 = nullptr;
        const float* rp2 = nullptr;
        if (k + 1 < NROW) {
            const int bh2 = (k + 1) * 512 + 2 * (int)blockIdx.x + rg;
            const size_t rowBase2 = (size_t)(bh2 >> 7) * CC * chanStride
                                  + (size_t)(bh2 & 127) * WW;
            lp2 = left  + rowBase2 + (size_t)(cg * 8) * chanStride + sw;
            rp2 = right + rowBase2 + (size_t)(cg * 8) * chanStride + sw;
            #pragma unroll
            for (int c = 0; c < 4; ++c)
                lv[c] = *(const float4*)(lp2 + (size_t)c * chanStride);
        }

        BAR();   // B: tiles staged (lgkmcnt-only; loads stay in flight)

        // Refill, group 2 of 4 (L chunks 4-7).
        if (k + 1 < NROW) {
            #pragma unroll
            for (int c = 4; c < 8; ++c)
                lv[c] = *(const float4*)(lp2 + (size_t)c * chanStride);
        }

        // ---------------- MFMA ----------------
        floatx4 acc[2][5];
        #pragma unroll
        for (int t = 0; t < 2; ++t)
            #pragma unroll
            for (int u = 0; u < 5; ++u)
                #pragma unroll
                for (int r = 0; r < 4; ++r)
                    acc[t][u][r] = 0.0f;

        #pragma unroll
        for (int kk = 0; kk < 2; ++kk) {
            const int col = ((kk * 4 + q) ^ (n & 7)) * 8;
            half8 bfrag[2], afrag[6];
            #pragma unroll
            for (int t = 0; t < 2; ++t)
                bfrag[t] = *(const half8*)&Lb[(wbase + t * 16 + n) * 64 + col];
            #pragma unroll
            for (int a = 0; a < 6; ++a)
                afrag[a] = *(const half8*)&Rb[(wbase + a * 16 + n) * 64 + col];
            #pragma unroll
            for (int t = 0; t < 2; ++t)
                #pragma unroll
                for (int u = 0; u < 5; ++u)
                    acc[t][u] = __builtin_amdgcn_mfma_f32_16x16x32_f16(
                        afrag[t + u], bfrag[t], acc[t][u], 0, 0, 0);

            // Refill, group 3 of 4 (R chunks 0-3) — between MFMA halves.
            if (kk == 0 && k + 1 < NROW) {
                #pragma unroll
                for (int c = 0; c < 4; ++c)
                    rv[c] = *(const float4*)(rp2 + (size_t)c * chanStride);
            }
        }
        BAR();   // C: all waves' fragment reads done; arenas dead

        // Refill, group 4 of 4 (R chunks 4-7).
        if (k + 1 < NROW) {
            #pragma unroll
            for (int c = 4; c < 8; ++c)
                rv[c] = *(const float4*)(rp2 + (size_t)c * chanStride);
        }

        // acc -> Ob[d][w] in this row-group's arena. d = 64-16u+n-m.
        #pragma unroll
        for (int t = 0; t < 2; ++t) {
            const int w = wbase + t * 16 + n;
            #pragma unroll
            for (int u = 0; u < 5; ++u) {
                #pragma unroll
                for (int r = 0; r < 4; ++r) {
                    const int d = 64 - 16 * u + n - (q * 4 + r);
                    if (d >= 0 && d < DD) {
                        Ob[d * OPITCH + w] = acc[t][u][r] * scale;
                    }
                }
            }
        }
        BAR();   // D: Ob complete (lgkmcnt-only)

        // Coalesced NT stores: wave wvl owns d = wvl*8..wvl*8+7 of its row;
        // each instruction writes one full 1KB row. The two row-groups
        // store h and h+1 -> adjacent 1KB output blocks, same MC-queue
        // pairing as the loads. Stores drain lazily under the next phase.
        #pragma unroll
        for (int i = 0; i < 8; ++i) {
            const int d = wvl * 8 + i;
            const floatx4 v = *(const floatx4*)&Ob[d * OPITCH + lane * 4];
            floatx4* dst = (floatx4*)&out[(((size_t)b * DD + d) * HH + h) * WW + lane * 4];
            __builtin_nontemporal_store(v, dst);
        }
    }
}

extern "C" void kernel_launch(void* const* d_in, const int* in_sizes, int n_in,
                              void* d_out, int out_size, void* d_ws, size_t ws_size,
                              hipStream_t stream) {
    const float* left  = (const float*)d_in[0];
    const float* right = (const float*)d_in[1];
    float* out = (float*)d_out;

    dim3 grid(GRID);    // 256 blocks = 1 per CU; 2 consecutive h-rows/phase
    dim3 block(1024);
    corr_volume_mfma<<<grid, block, 0, stream>>>(left, right, out);
}